// Round 1
// baseline (450.990 us; speedup 1.0000x reference)
//
#include <hip/hip_runtime.h>
#include <stdint.h>

#define B_ROWS 16384
#define NF 26
#define NV 100000
#define NN 13
#define ND 32
#define K1DIM 1248   // (26+13)*32
#define H1DIM 256
#define H2DIM 128
#define H3DIM 64

typedef float f32x4 __attribute__((ext_vector_type(4)));
typedef short bf16x8 __attribute__((ext_vector_type(8)));

static __device__ __forceinline__ unsigned short f2bf(float f) {
    unsigned int u = __float_as_uint(f);
    unsigned int r = (u + 0x7fffu + ((u >> 16) & 1u)) >> 16;
    return (unsigned short)r;
}

// ---------------- repack W1/W2/W3 fp32 (K,N) -> bf16 packed [kt][n][kk] ----------------
#define S1P ((K1DIM/32)*H1DIM*32)   // 319488
#define S2P ((H1DIM/32)*H2DIM*32)   // 32768
#define S3P ((H2DIM/32)*H3DIM*32)   // 8192

__global__ __launch_bounds__(256) void repack_weights(
    const float* __restrict__ W1, const float* __restrict__ W2, const float* __restrict__ W3,
    unsigned short* __restrict__ W1p, unsigned short* __restrict__ W2p, unsigned short* __restrict__ W3p)
{
    int tid = blockIdx.x * 256 + threadIdx.x;
    if (tid < S1P) {
        int kk = tid & 31; int n = (tid >> 5) & (H1DIM - 1); int kt = tid >> 13;
        W1p[tid] = f2bf(W1[(kt * 32 + kk) * H1DIM + n]);
    } else if (tid < S1P + S2P) {
        int t = tid - S1P;
        int kk = t & 31; int n = (t >> 5) & (H2DIM - 1); int kt = t >> 12;
        W2p[t] = f2bf(W2[(kt * 32 + kk) * H2DIM + n]);
    } else if (tid < S1P + S2P + S3P) {
        int t = tid - S1P - S2P;
        int kk = t & 31; int n = (t >> 5) & (H3DIM - 1); int kt = t >> 11;
        W3p[t] = f2bf(W3[(kt * 32 + kk) * H3DIM + n]);
    }
}

// ---------------- fused embedding gather + FM 2nd order + linear term ----------------
// 32 lanes per row (lane = embedding dim d), 8 rows per 256-thread block.
__global__ __launch_bounds__(256) void embed_fm(
    const int* __restrict__ x_cat, const float* __restrict__ x_num,
    const float* __restrict__ emb0, const float* __restrict__ emb1,
    const float* __restrict__ num_bias, const float* __restrict__ num_emb,
    unsigned short* __restrict__ Xp, float* __restrict__ lin_out, float* __restrict__ fm_out)
{
    int grp = threadIdx.x >> 5;
    int d   = threadIdx.x & 31;
    int row = blockIdx.x * 8 + grp;

    const int* xc = x_cat + row * NF;
    int   myidx = (d < NF) ? xc[d] : 0;
    float xn    = (d < NN) ? x_num[row * NN + d] : 0.f;

    float lv = 0.f;
    if (d < NF) lv = emb0[d * NV + myidx];
    if (d < NN) lv += xn * num_bias[d];

    unsigned short* xr = Xp + (size_t)row * K1DIM;
    float s = 0.f, q = 0.f;
#pragma unroll
    for (int f = 0; f < NF; ++f) {
        int idx = __shfl(myidx, f, 32);
        float e = emb1[((size_t)(f * NV + idx)) * ND + d];
        s += e; q += e * e;
        xr[f * ND + d] = f2bf(e);
    }
#pragma unroll
    for (int n = 0; n < NN; ++n) {
        float xv = __shfl(xn, n, 32);
        float e = xv * num_emb[n * ND + d];
        s += e; q += e * e;
        xr[(NF + n) * ND + d] = f2bf(e);
    }
    float val = s * s - q;
#pragma unroll
    for (int m = 16; m >= 1; m >>= 1) {
        val += __shfl_xor(val, m, 32);
        lv  += __shfl_xor(lv,  m, 32);
    }
    if (d == 0) { fm_out[row] = 0.5f * val; lin_out[row] = lv; }
}

// ---------------- bf16 MFMA GEMM + bias + relu -> bf16 ----------------
// X: (M,K) row-major bf16.  Wp: packed [kt][n][kk].  Y: (M,N) row-major bf16.
// Per wave: (TMM*16) rows x (TMN*16) cols. 4 waves/block share the same rows.
template<int TMM, int TMN>
__global__ __launch_bounds__(256) void gemm_relu(
    const unsigned short* __restrict__ X, const unsigned short* __restrict__ Wp,
    const float* __restrict__ bias, unsigned short* __restrict__ Y,
    int M, int N, int K)
{
    int wave = blockIdx.x * 4 + (threadIdx.x >> 6);
    int lane = threadIdx.x & 63;
    int l15 = lane & 15, quad = lane >> 4;
    int nWaveN = N / (16 * TMN);
    int wm = wave / nWaveN, wn = wave % nWaveN;
    int m0 = wm * 16 * TMM, n0 = wn * 16 * TMN;

    f32x4 acc[TMM][TMN];
#pragma unroll
    for (int i = 0; i < TMM; i++)
#pragma unroll
        for (int j = 0; j < TMN; j++) acc[i][j] = (f32x4){0.f, 0.f, 0.f, 0.f};

    const unsigned short* aptr = X + (size_t)(m0 + l15) * K + quad * 8;
    const unsigned short* bptr = Wp + ((size_t)n0 + l15) * 32 + quad * 8;
    int KT = K >> 5;
    for (int kt = 0; kt < KT; ++kt) {
        bf16x8 a[TMM], b[TMN];
#pragma unroll
        for (int i = 0; i < TMM; i++)
            a[i] = *(const bf16x8*)(aptr + (size_t)i * 16 * K + kt * 32);
#pragma unroll
        for (int j = 0; j < TMN; j++)
            b[j] = *(const bf16x8*)(bptr + ((size_t)kt * N + j * 16) * 32);
#pragma unroll
        for (int i = 0; i < TMM; i++)
#pragma unroll
            for (int j = 0; j < TMN; j++)
                acc[i][j] = __builtin_amdgcn_mfma_f32_16x16x32_bf16(a[i], b[j], acc[i][j], 0, 0, 0);
    }
#pragma unroll
    for (int j = 0; j < TMN; j++) {
        int col = n0 + j * 16 + l15;
        float bv = bias[col];
#pragma unroll
        for (int i = 0; i < TMM; i++) {
            int rbase = m0 + i * 16 + quad * 4;
#pragma unroll
            for (int r = 0; r < 4; r++) {
                float v = acc[i][j][r] + bv;
                v = v > 0.f ? v : 0.f;
                Y[(size_t)(rbase + r) * N + col] = f2bf(v);
            }
        }
    }
}

// ---------------- GEMM3 (128->64) + relu + both heads ----------------
__global__ __launch_bounds__(256) void gemm_head(
    const unsigned short* __restrict__ X, const unsigned short* __restrict__ Wp,
    const float* __restrict__ b3,
    const float* __restrict__ Wc, const float* __restrict__ bc,
    const float* __restrict__ Wo, const float* __restrict__ bo,
    const float* __restrict__ lin, const float* __restrict__ fm,
    float* __restrict__ out)
{
    const int K = H2DIM, N = H3DIM;
    int wave = blockIdx.x * 4 + (threadIdx.x >> 6);
    int lane = threadIdx.x & 63;
    int l15 = lane & 15, quad = lane >> 4;
    int m0 = wave * 16;

    f32x4 acc[4];
#pragma unroll
    for (int j = 0; j < 4; j++) acc[j] = (f32x4){0.f, 0.f, 0.f, 0.f};

    const unsigned short* aptr = X + (size_t)(m0 + l15) * K + quad * 8;
    const unsigned short* bptr = Wp + (size_t)l15 * 32 + quad * 8;
#pragma unroll
    for (int kt = 0; kt < 4; ++kt) {
        bf16x8 a = *(const bf16x8*)(aptr + kt * 32);
#pragma unroll
        for (int j = 0; j < 4; j++) {
            bf16x8 b = *(const bf16x8*)(bptr + (kt * N + j * 16) * 32);
            acc[j] = __builtin_amdgcn_mfma_f32_16x16x32_bf16(a, b, acc[j], 0, 0, 0);
        }
    }

    float s1r[4] = {0.f, 0.f, 0.f, 0.f};
    float s2r[4] = {0.f, 0.f, 0.f, 0.f};
#pragma unroll
    for (int j = 0; j < 4; j++) {
        int col = j * 16 + l15;
        float bv = b3[col], wc = Wc[col], wo = Wo[col];
#pragma unroll
        for (int r = 0; r < 4; r++) {
            float v = acc[j][r] + bv;
            v = v > 0.f ? v : 0.f;
            s1r[r] += v * wc;
            s2r[r] += v * wo;
        }
    }
#pragma unroll
    for (int r = 0; r < 4; r++) {
#pragma unroll
        for (int m = 8; m >= 1; m >>= 1) {
            s1r[r] += __shfl_xor(s1r[r], m, 16);
            s2r[r] += __shfl_xor(s2r[r], m, 16);
        }
    }
    if (l15 == 0) {
        float wc64 = Wc[64], wc65 = Wc[65], wo64 = Wo[64], wo65 = Wo[65];
        float bcv = bc[0], bov = bo[0];
#pragma unroll
        for (int r = 0; r < 4; r++) {
            int row = m0 + quad * 4 + r;
            float lt = lin[row], f2 = fm[row];
            out[row]          = s1r[r] + lt * wc64 + f2 * wc65 + bcv;
            out[B_ROWS + row] = s2r[r] + lt * wo64 + f2 * wo65 + bov;
        }
    }
}

// ---------------- workspace layout (bytes) ----------------
#define OFF_XP   ((size_t)0)
#define OFF_W1P  ((size_t)40894464)            // 16384*1248*2
#define OFF_W2P  (OFF_W1P + 638976)            // S1P*2
#define OFF_W3P  (OFF_W2P + 65536)             // S2P*2
#define OFF_H1   (OFF_W3P + 16384)             // S3P*2
#define OFF_H2   (OFF_H1 + 8388608)            // 16384*256*2
#define OFF_LIN  (OFF_H2 + 4194304)            // 16384*128*2
#define OFF_FM   (OFF_LIN + 65536)
// total = OFF_FM + 65536 = 54329344 bytes (~54.3 MB)

extern "C" void kernel_launch(void* const* d_in, const int* in_sizes, int n_in,
                              void* d_out, int out_size, void* d_ws, size_t ws_size,
                              hipStream_t stream)
{
    const int*   x_cat    = (const int*)d_in[0];
    const float* x_num    = (const float*)d_in[1];
    const float* emb0     = (const float*)d_in[2];
    const float* emb1     = (const float*)d_in[3];
    const float* num_bias = (const float*)d_in[4];
    const float* num_emb  = (const float*)d_in[5];
    const float* W1 = (const float*)d_in[6];
    const float* b1 = (const float*)d_in[7];
    const float* W2 = (const float*)d_in[8];
    const float* b2 = (const float*)d_in[9];
    const float* W3 = (const float*)d_in[10];
    const float* b3 = (const float*)d_in[11];
    const float* Wc = (const float*)d_in[12];
    const float* bc = (const float*)d_in[13];
    const float* Wo = (const float*)d_in[14];
    const float* bo = (const float*)d_in[15];
    float* out = (float*)d_out;

    char* ws = (char*)d_ws;
    unsigned short* Xp  = (unsigned short*)(ws + OFF_XP);
    unsigned short* W1p = (unsigned short*)(ws + OFF_W1P);
    unsigned short* W2p = (unsigned short*)(ws + OFF_W2P);
    unsigned short* W3p = (unsigned short*)(ws + OFF_W3P);
    unsigned short* H1  = (unsigned short*)(ws + OFF_H1);
    unsigned short* H2  = (unsigned short*)(ws + OFF_H2);
    float* lin = (float*)(ws + OFF_LIN);
    float* fm  = (float*)(ws + OFF_FM);

    repack_weights<<<(S1P + S2P + S3P) / 256, 256, 0, stream>>>(W1, W2, W3, W1p, W2p, W3p);
    embed_fm<<<B_ROWS / 8, 256, 0, stream>>>(x_cat, x_num, emb0, emb1, num_bias, num_emb, Xp, lin, fm);
    // L1: (16384,1248)@(1248,256): 64x64 per wave -> 1024 waves -> 256 blocks
    gemm_relu<4, 4><<<256, 256, 0, stream>>>(Xp, W1p, b1, H1, B_ROWS, H1DIM, K1DIM);
    // L2: (16384,256)@(256,128): 32x32 per wave -> 2048 waves -> 512 blocks
    gemm_relu<2, 2><<<512, 256, 0, stream>>>(H1, W2p, b2, H2, B_ROWS, H2DIM, H1DIM);
    // L3 + heads: 16 rows per wave -> 1024 waves -> 256 blocks
    gemm_head<<<B_ROWS / 16 / 4, 256, 0, stream>>>(H2, W3p, b3, Wc, bc, Wo, bo, lin, fm, out);
}